// Round 6
// baseline (221.475 us; speedup 1.0000x reference)
//
#include <hip/hip_runtime.h>
#include <hip/hip_bf16.h>

#define BB 64
#define TT 1024
#define NN 512
#define LISTCAP (1u << 18)

static constexpr float THR = 0.15f;

typedef __attribute__((ext_vector_type(8))) short bf16x8;
typedef __attribute__((ext_vector_type(4))) float f32x4;

// ---------------- kernel T: fused colsum + fp32->bf16 transpose ----------------
// Grid (BB, 8): block b, ng -> 64 cols. 512 thr = 8 waves. Produces:
//   xbf[b][col][t]  (bf16 RTZ high part, t contiguous -> corr frags are 16B loads)
//   s1, dv, nv=||x||, nl=||l|| per column (l = v - rtz_bf16(v), exact residual).
// Per 512-t chunk: thread (w,l) owns col n0+l, t's {i*64 + w*8 + j}; reads coalesced
// (64 lanes x 4B consecutive n), packs 8 t's -> ds_write_b128 into col-major tile
// with self-inverting XOR swizzle byte = c*1024 + (tl*2 ^ ((c&7)<<4)):
//   - write: 8 lanes per 4-bank group, 8 cyc = floor (conflict-free)
//   - read-out (lane l reads 16B at (16l ^ swz)): full-col permutation, floor
//   - read at (16l ^ swz) returns t-bytes 16l -> PLAIN order; global writes are
//     1 KB contiguous per wave-instruction, xbf ends up unswizzled.
__global__ __launch_bounds__(512) void transpose_colsum(
    const float* __restrict__ x, ushort* __restrict__ xbf,
    float* __restrict__ s1, float* __restrict__ dv,
    float* __restrict__ nv, float* __restrict__ nl) {
    __shared__ ushort tile[64 * 512];       // 64 KiB
    __shared__ float red[3][8][64];         // 6 KiB
    int b = blockIdx.x, ng = blockIdx.y;
    int n0 = ng * 64;
    int tid = threadIdx.x, w = tid >> 6, l = tid & 63;
    const float* xb = x + (size_t)b * TT * NN;
    float a1 = 0.f, a2 = 0.f, al = 0.f;
    unsigned swz = ((unsigned)l & 7u) << 4;

    for (int tc = 0; tc < 2; ++tc) {
        for (int i = 0; i < 8; ++i) {
            int tl0 = i * 64 + w * 8;           // local t of this thread's 8-run
            int t0 = tc * 512 + tl0;
            unsigned hp[4];
            #pragma unroll
            for (int q = 0; q < 4; ++q) {
                float v0 = xb[(size_t)(t0 + 2 * q) * NN + n0 + l];
                float v1 = xb[(size_t)(t0 + 2 * q + 1) * NN + n0 + l];
                a1 += v0 + v1;
                a2 += v0 * v0 + v1 * v1;
                unsigned u0 = __float_as_uint(v0), u1 = __float_as_uint(v1);
                float h0 = __uint_as_float(u0 & 0xFFFF0000u);
                float h1 = __uint_as_float(u1 & 0xFFFF0000u);
                float l0 = v0 - h0, l1 = v1 - h1;   // exact residuals
                al += l0 * l0 + l1 * l1;
                hp[q] = (u0 >> 16) | (u1 & 0xFFFF0000u);
            }
            unsigned off = (unsigned)l * 1024u + (((unsigned)tl0 * 2u) ^ swz);
            *(uint4*)((char*)tile + off) = make_uint4(hp[0], hp[1], hp[2], hp[3]);
        }
        __syncthreads();
        // write-out: wave w -> cols 8w..8w+7; lane l -> t-bytes [16l,16l+16)
        #pragma unroll
        for (int cc = 0; cc < 8; ++cc) {
            int cl = w * 8 + cc;
            unsigned src = (unsigned)cl * 1024u
                           + (((unsigned)l * 16u) ^ (((unsigned)cl & 7u) << 4));
            uint4 val = *(const uint4*)((char*)tile + src);
            ushort* dst = xbf + ((size_t)(b * NN + n0 + cl) * TT + tc * 512 + l * 8);
            *(uint4*)dst = val;
        }
        __syncthreads();
    }
    red[0][w][l] = a1; red[1][w][l] = a2; red[2][w][l] = al;
    __syncthreads();
    if (tid < 64) {
        float r1 = 0.f, r2 = 0.f, rl = 0.f;
        #pragma unroll
        for (int k = 0; k < 8; ++k) {
            r1 += red[0][k][tid]; r2 += red[1][k][tid]; rl += red[2][k][tid];
        }
        size_t o = (size_t)b * NN + n0 + tid;
        s1[o] = r1;
        dv[o] = r2 - r1 * r1 * (1.0f / TT);   // cov_ii (unnormalized)
        nv[o] = sqrtf(r2);
        nl[o] = sqrtf(rl);
    }
}

// ---------------- kernel B: barrier-free MFMA SYRK from transposed bf16 ----------------
// 128x128 tile per block; 10 upper tiles x 64 batches = 640 blocks (XCD-chunked
// swizzle kept); 512 thr = 8 fully-INDEPENDENT waves, wave-tile 32x64. No LDS, no
// barriers, no staging: each lane's fragment (8 consecutive k of one col) is one
// global_load_dwordx4 from xbf with immediate offsets (32 steps x 64B < 4095).
// Per wave K-step: 6 loads + 8 MFMA. Panels shared by waves hit L1/L2.
// Epilogue: r5's verified certainty bound + uncertain-pair list (absmax 0).
__global__ __launch_bounds__(512) void corr_mfma(
    const ushort* __restrict__ xbf, const float* __restrict__ s1,
    const float* __restrict__ dv, const float* __restrict__ nv,
    const float* __restrict__ nl, unsigned* __restrict__ fired,
    unsigned* __restrict__ cnt, unsigned* __restrict__ list) {
    int id = blockIdx.x;
    int swz = ((id & 7) * 80) + (id >> 3);
    int b = swz / 10;
    int u = swz % 10;
    int ti = 0, rem = u;
    while (rem >= (4 - ti)) { rem -= (4 - ti); ++ti; }
    int tj = ti + rem;
    int i0 = ti * 128, j0 = tj * 128;
    bool diag = (ti == tj);

    int tid = threadIdx.x;
    int wave = tid >> 6, lane = tid & 63;
    int rl = lane & 15, kg = lane >> 4;
    int wr = wave >> 1, wc = wave & 1;
    bool skip_mm = diag && (wc == 0) && (wr >= 2);   // fully below diagonal

    const ushort* xb = xbf + (size_t)b * NN * TT;
    const char* pA[2];
    const char* pB[4];
    #pragma unroll
    for (int f = 0; f < 2; ++f) {
        int colA = i0 + 32 * wr + 16 * f + rl;
        pA[f] = (const char*)(xb + (size_t)colA * TT + kg * 8);
    }
    #pragma unroll
    for (int f = 0; f < 4; ++f) {
        int colB = j0 + 64 * wc + 16 * f + rl;
        pB[f] = (const char*)(xb + (size_t)colB * TT + kg * 8);
    }

    f32x4 acc[2][4];
    #pragma unroll
    for (int i = 0; i < 2; ++i)
        #pragma unroll
        for (int j = 0; j < 4; ++j)
            acc[i][j] = (f32x4)0.0f;

    if (!skip_mm) {
        #pragma unroll 8
        for (int s = 0; s < 32; ++s) {
            bf16x8 A[2], Bv[4];
            #pragma unroll
            for (int f = 0; f < 2; ++f) A[f] = *(const bf16x8*)(pA[f] + s * 64);
            #pragma unroll
            for (int f = 0; f < 4; ++f) Bv[f] = *(const bf16x8*)(pB[f] + s * 64);
            #pragma unroll
            for (int fj = 0; fj < 4; ++fj)
                #pragma unroll
                for (int fi = 0; fi < 2; ++fi)
                    acc[fi][fj] = __builtin_amdgcn_mfma_f32_16x16x32_bf16(
                        A[fi], Bv[fj], acc[fi][fj], 0, 0, 0);
        }
    }

    // ---- epilogue: c = acc - s1_i*s1_j/T;  lim = thr^2*d_i*d_j ----
    const float thr2 = THR * THR;
    const float invT = 1.0f / TT;
    const float* s1b = s1 + (size_t)b * NN;
    const float* dvb = dv + (size_t)b * NN;
    const float* nvb = nv + (size_t)b * NN;
    const float* nlb = nl + (size_t)b * NN;
    unsigned* fb = fired + (size_t)b * NN;
    int rowb = i0 + 32 * wr + (lane >> 4) * 4;
    int colb = j0 + 64 * wc + rl;
    #pragma unroll
    for (int fj = 0; fj < 4; ++fj) {
        int gj = colb + 16 * fj;
        float sj = s1b[gj], djv = dvb[gj];
        float nvj = nvb[gj], nlj = nlb[gj];
        #pragma unroll
        for (int fi = 0; fi < 2; ++fi) {
            int gi0 = rowb + 16 * fi;
            #pragma unroll
            for (int r = 0; r < 4; ++r) {
                int gi = gi0 + r;
                if (gj > gi) {
                    float c = acc[fi][fj][r] - s1b[gi] * sj * invT;
                    float lim = thr2 * dvb[gi] * djv;
                    float nvi = nvb[gi], nli = nlb[gi];
                    float B = nli * nvj + nlj * nvi + 3.0f * nli * nlj
                              + 1e-3f * nvi * nvj;
                    float a = fabsf(c);
                    float lo = a - B;
                    if (lo > 0.0f && lo * lo > lim) {
                        atomicOr(&fb[gi], 1u);
                    } else if ((a + B) * (a + B) > lim) {
                        unsigned idx = atomicAdd(cnt, 1u);
                        if (idx < LISTCAP)
                            list[idx] = ((unsigned)b << 18) | ((unsigned)gi << 9)
                                        | (unsigned)gj;
                    }
                }
            }
        }
    }
}

// ---------------- kernel B2: exact recompute of borderline pairs ----------------
__global__ __launch_bounds__(256) void cleanup_pairs(
    const float* __restrict__ x, const float* __restrict__ s1,
    const float* __restrict__ dv, const unsigned* __restrict__ cnt,
    const unsigned* __restrict__ list, unsigned* __restrict__ fired) {
    unsigned n = *cnt;
    if (n > LISTCAP) n = LISTCAP;
    int lane = threadIdx.x & 63;
    int gw = (blockIdx.x * 256 + threadIdx.x) >> 6;
    int nw = (gridDim.x * 256) >> 6;
    for (unsigned p = gw; p < n; p += nw) {
        unsigned e = list[p];
        int b = e >> 18, i = (e >> 9) & 511, j = e & 511;
        const float* xb = x + (size_t)b * TT * NN;
        double s = 0.0;
        for (int t = lane; t < TT; t += 64)
            s += (double)xb[(size_t)t * NN + i] * (double)xb[(size_t)t * NN + j];
        #pragma unroll
        for (int o = 32; o > 0; o >>= 1)
            s += __shfl_xor(s, o, 64);
        if (lane == 0) {
            double cov = s - (double)s1[(size_t)b * NN + i]
                             * (double)s1[(size_t)b * NN + j] / (double)TT;
            double lim = (double)THR * (double)THR
                         * (double)dv[(size_t)b * NN + i]
                         * (double)dv[(size_t)b * NN + j];
            if (cov * cov > lim) atomicOr(&fired[(size_t)b * NN + i], 1u);
        }
    }
}

// ---------------- kernel C: finalize mask ----------------
__global__ __launch_bounds__(512) void finalize_mask(
    const unsigned* __restrict__ fired, float* __restrict__ out) {
    int b = blockIdx.x;
    int n = threadIdx.x;                  // 512
    unsigned f = fired[(size_t)b * NN + n];
    __shared__ int wsum[8];
    unsigned long long m = __ballot(f != 0u);
    int lane = n & 63;
    int w = n >> 6;
    if (lane == 0) wsum[w] = __popcll(m);
    __syncthreads();
    int cnt = 0;
    #pragma unroll
    for (int i = 0; i < 8; ++i) cnt += wsum[i];
    float val = (cnt == 0) ? 1.0f : ((cnt == 1) ? (f ? 1.0f : 0.0f) : 0.0f);
    out[(size_t)b * NN + n] = val;
}

extern "C" void kernel_launch(void* const* d_in, const int* in_sizes, int n_in,
                              void* d_out, int out_size, void* d_ws, size_t ws_size,
                              hipStream_t stream) {
    const float* x = (const float*)d_in[0];
    float* out = (float*)d_out;

    // ws layout (~66 MB)
    ushort* xbf = (ushort*)d_ws;                         // BB*NN*TT bf16 = 64 MB
    float* s1 = (float*)(xbf + (size_t)BB * NN * TT);    // B*N
    float* dv = s1 + (size_t)BB * NN;                    // B*N
    float* nv = dv + (size_t)BB * NN;                    // B*N
    float* nl = nv + (size_t)BB * NN;                    // B*N
    unsigned* fired = (unsigned*)(nl + (size_t)BB * NN); // B*N
    unsigned* cnt   = fired + (size_t)BB * NN;           // 16 (padded)
    unsigned* list  = cnt + 16;                          // LISTCAP

    hipMemsetAsync(fired, 0, ((size_t)BB * NN + 16) * sizeof(unsigned), stream);

    transpose_colsum<<<dim3(BB, 8), 512, 0, stream>>>(x, xbf, s1, dv, nv, nl);
    corr_mfma<<<dim3(640), 512, 0, stream>>>(xbf, s1, dv, nv, nl, fired, cnt, list);
    cleanup_pairs<<<128, 256, 0, stream>>>(x, s1, dv, cnt, list, fired);
    finalize_mask<<<BB, 512, 0, stream>>>(fired, out);
}

// Round 7
// 84.524 us; speedup vs baseline: 2.6203x; 2.6203x over previous
//
#include <hip/hip_runtime.h>
#include <hip/hip_bf16.h>

#define BB 64
#define TT 1024
#define NN 512
#define LISTCAP (1u << 18)

static constexpr float THR = 0.15f;

typedef __attribute__((ext_vector_type(8))) short bf16x8;
typedef __attribute__((ext_vector_type(4))) float f32x4;

// async global->LDS, 16B per lane; dest = wave-uniform base + lane*16 (HW rule)
__device__ __forceinline__ void gload16(const void* g, void* lds_dst) {
    __builtin_amdgcn_global_load_lds(
        (const __attribute__((address_space(1))) unsigned int*)g,
        (__attribute__((address_space(3))) unsigned int*)lds_dst, 16, 0, 0);
}

// ---------------- kernel T: fused colsum + fp32->bf16 transpose ----------------
// (verified round 6, HBM-roofline-bound ~35us). Produces xbf[b][col][t] bf16 RTZ,
// t contiguous, plus s1, dv, nv=||x||, nl=||l|| per column.
__global__ __launch_bounds__(512) void transpose_colsum(
    const float* __restrict__ x, ushort* __restrict__ xbf,
    float* __restrict__ s1, float* __restrict__ dv,
    float* __restrict__ nv, float* __restrict__ nl) {
    __shared__ ushort tile[64 * 512];       // 64 KiB
    __shared__ float red[3][8][64];         // 6 KiB
    int b = blockIdx.x, ng = blockIdx.y;
    int n0 = ng * 64;
    int tid = threadIdx.x, w = tid >> 6, l = tid & 63;
    const float* xb = x + (size_t)b * TT * NN;
    float a1 = 0.f, a2 = 0.f, al = 0.f;
    unsigned swz = ((unsigned)l & 7u) << 4;

    for (int tc = 0; tc < 2; ++tc) {
        for (int i = 0; i < 8; ++i) {
            int tl0 = i * 64 + w * 8;
            int t0 = tc * 512 + tl0;
            unsigned hp[4];
            #pragma unroll
            for (int q = 0; q < 4; ++q) {
                float v0 = xb[(size_t)(t0 + 2 * q) * NN + n0 + l];
                float v1 = xb[(size_t)(t0 + 2 * q + 1) * NN + n0 + l];
                a1 += v0 + v1;
                a2 += v0 * v0 + v1 * v1;
                unsigned u0 = __float_as_uint(v0), u1 = __float_as_uint(v1);
                float h0 = __uint_as_float(u0 & 0xFFFF0000u);
                float h1 = __uint_as_float(u1 & 0xFFFF0000u);
                float l0 = v0 - h0, l1 = v1 - h1;   // exact residuals
                al += l0 * l0 + l1 * l1;
                hp[q] = (u0 >> 16) | (u1 & 0xFFFF0000u);
            }
            unsigned off = (unsigned)l * 1024u + (((unsigned)tl0 * 2u) ^ swz);
            *(uint4*)((char*)tile + off) = make_uint4(hp[0], hp[1], hp[2], hp[3]);
        }
        __syncthreads();
        #pragma unroll
        for (int cc = 0; cc < 8; ++cc) {
            int cl = w * 8 + cc;
            unsigned src = (unsigned)cl * 1024u
                           + (((unsigned)l * 16u) ^ (((unsigned)cl & 7u) << 4));
            uint4 val = *(const uint4*)((char*)tile + src);
            ushort* dst = xbf + ((size_t)(b * NN + n0 + cl) * TT + tc * 512 + l * 8);
            *(uint4*)dst = val;
        }
        __syncthreads();
    }
    red[0][w][l] = a1; red[1][w][l] = a2; red[2][w][l] = al;
    __syncthreads();
    if (tid < 64) {
        float r1 = 0.f, r2 = 0.f, rl = 0.f;
        #pragma unroll
        for (int k = 0; k < 8; ++k) {
            r1 += red[0][k][tid]; r2 += red[1][k][tid]; rl += red[2][k][tid];
        }
        size_t o = (size_t)b * NN + n0 + tid;
        s1[o] = r1;
        dv[o] = r2 - r1 * r1 * (1.0f / TT);
        nv[o] = sqrtf(r2);
        nl[o] = sqrtf(rl);
    }
}

// ---------------- kernel B: MFMA SYRK, global_load_lds staging, KT=64 ----------------
// 128x128 tile/block; 10 upper tiles x 64 batches = 640 blocks (XCD-chunked swizzle);
// 512 thr = 8 waves, wave-tile 32x64. m97-structure: single 32 KiB LDS buffer =
// 4 subtiles [ks][panel] of 8 KiB, each in the r5-VERIFIED conflict-free layout
//   byte(col,k') = col*64 + (((k'>>3) ^ ((col>>1)&3))&3)*16 + (k'&7)*2,  k' = k&31.
// Staging = 4 global_load_lds dwordx4 per thread per K-step (zero pack VALU, zero
// ds_write): LDS linear dest (tid*16 within subtile), SOURCE pre-swizzled
// (rule #21): lane covers col c = tid>>2, k-octet kk = (tid&3) ^ ((c>>1)&3).
// KT=64 halves barrier pairs vs r5 (16 vs 32): 16 MFMA per wave per barrier-pair.
// Epilogue: r5-verified certainty bound (Cauchy-Schwarz on RTZ residual norms)
// + uncertain-pair list -> exact cleanup.
__global__ __launch_bounds__(512) void corr_mfma(
    const ushort* __restrict__ xbf, const float* __restrict__ s1,
    const float* __restrict__ dv, const float* __restrict__ nv,
    const float* __restrict__ nl, unsigned* __restrict__ fired,
    unsigned* __restrict__ cnt, unsigned* __restrict__ list) {
    __shared__ uint4 ldsbuf[2048];          // 32 KiB = 4 x 8 KiB subtiles
    char* base = (char*)ldsbuf;

    int id = blockIdx.x;
    int swz = ((id & 7) * 80) + (id >> 3);
    int b = swz / 10;
    int u = swz % 10;
    int ti = 0, rem = u;
    while (rem >= (4 - ti)) { rem -= (4 - ti); ++ti; }
    int tj = ti + rem;
    int i0 = ti * 128, j0 = tj * 128;
    bool diag = (ti == tj);

    int tid = threadIdx.x;
    int wave = tid >> 6, lane = tid & 63;
    int rl = lane & 15, kg = lane >> 4;

    // ---- staging source addresses (per-lane, pre-swizzled) ----
    int c = tid >> 2;                       // column within panel 0..127
    int slot = tid & 3;
    int kk = slot ^ ((c >> 1) & 3);         // k-octet content for this LDS slot
    const ushort* xb = xbf + (size_t)b * NN * TT;
    const ushort* gsrc[4];
    char* ldst[4];
    #pragma unroll
    for (int L = 0; L < 4; ++L) {
        int ks = L >> 1, pan = L & 1;
        int col = (pan ? j0 : i0) + c;
        gsrc[L] = xb + (size_t)col * TT + ks * 32 + kk * 8;
        ldst[L] = base + L * 8192 + wave * 1024;   // wave-uniform base
    }

    // ---- compute role: wave (wr, wc) owns rows [32*wr,+32) x cols [64*wc,+64) ----
    int wr = wave >> 1, wc = wave & 1;
    bool skip_mm = diag && (wc == 0) && (wr >= 2);

    f32x4 acc[2][4];
    #pragma unroll
    for (int i = 0; i < 2; ++i)
        #pragma unroll
        for (int j = 0; j < 4; ++j)
            acc[i][j] = (f32x4)0.0f;

    unsigned aoff[2], boff[4];
    #pragma unroll
    for (int f = 0; f < 2; ++f) {
        unsigned ca = (unsigned)(32 * wr + 16 * f + rl);
        aoff[f] = ca * 64u + ((((unsigned)kg ^ ((ca >> 1) & 3u)) & 3u) << 4);
    }
    #pragma unroll
    for (int f = 0; f < 4; ++f) {
        unsigned cb = (unsigned)(64 * wc + 16 * f + rl);
        boff[f] = cb * 64u + ((((unsigned)kg ^ ((cb >> 1) & 3u)) & 3u) << 4);
    }
    // subtile bases: index = ks*2 + panel; diag reads B from the A subtile
    unsigned asub[2] = { 0u, 16384u };
    unsigned bsub[2] = { diag ? 0u : 8192u, diag ? 16384u : 24576u };

    for (int t0 = 0; t0 < TT; t0 += 64) {
        #pragma unroll
        for (int L = 0; L < 4; ++L)
            if (!(diag && (L & 1)))
                gload16(gsrc[L] + t0, ldst[L]);
        __syncthreads();                     // drains vmcnt: LDS tiles ready
        #pragma unroll
        for (int ks = 0; ks < 2; ++ks) {
            if (!skip_mm) {
                bf16x8 A[2];
                #pragma unroll
                for (int f = 0; f < 2; ++f)
                    A[f] = *(const bf16x8*)(base + asub[ks] + aoff[f]);
                #pragma unroll
                for (int fj = 0; fj < 4; ++fj) {
                    bf16x8 Bh = *(const bf16x8*)(base + bsub[ks] + boff[fj]);
                    #pragma unroll
                    for (int fi = 0; fi < 2; ++fi)
                        acc[fi][fj] = __builtin_amdgcn_mfma_f32_16x16x32_bf16(
                            A[fi], Bh, acc[fi][fj], 0, 0, 0);
                }
            }
        }
        __syncthreads();
    }

    // ---- epilogue: c = acc - s1_i*s1_j/T;  lim = thr^2*d_i*d_j ----
    const float thr2 = THR * THR;
    const float invT = 1.0f / TT;
    const float* s1b = s1 + (size_t)b * NN;
    const float* dvb = dv + (size_t)b * NN;
    const float* nvb = nv + (size_t)b * NN;
    const float* nlb = nl + (size_t)b * NN;
    unsigned* fb = fired + (size_t)b * NN;
    int rowb = i0 + 32 * wr + (lane >> 4) * 4;
    int colb = j0 + 64 * wc + rl;
    #pragma unroll
    for (int fj = 0; fj < 4; ++fj) {
        int gj = colb + 16 * fj;
        float sj = s1b[gj], djv = dvb[gj];
        float nvj = nvb[gj], nlj = nlb[gj];
        #pragma unroll
        for (int fi = 0; fi < 2; ++fi) {
            int gi0 = rowb + 16 * fi;
            #pragma unroll
            for (int r = 0; r < 4; ++r) {
                int gi = gi0 + r;
                if (gj > gi) {
                    float cc = acc[fi][fj][r] - s1b[gi] * sj * invT;
                    float lim = thr2 * dvb[gi] * djv;
                    float nvi = nvb[gi], nli = nlb[gi];
                    float B = nli * nvj + nlj * nvi + 3.0f * nli * nlj
                              + 1e-3f * nvi * nvj;
                    float a = fabsf(cc);
                    float lo = a - B;
                    if (lo > 0.0f && lo * lo > lim) {
                        atomicOr(&fb[gi], 1u);
                    } else if ((a + B) * (a + B) > lim) {
                        unsigned idx = atomicAdd(cnt, 1u);
                        if (idx < LISTCAP)
                            list[idx] = ((unsigned)b << 18) | ((unsigned)gi << 9)
                                        | (unsigned)gj;
                    }
                }
            }
        }
    }
}

// ---------------- kernel B2: exact recompute of borderline pairs ----------------
__global__ __launch_bounds__(256) void cleanup_pairs(
    const float* __restrict__ x, const float* __restrict__ s1,
    const float* __restrict__ dv, const unsigned* __restrict__ cnt,
    const unsigned* __restrict__ list, unsigned* __restrict__ fired) {
    unsigned n = *cnt;
    if (n > LISTCAP) n = LISTCAP;
    int lane = threadIdx.x & 63;
    int gw = (blockIdx.x * 256 + threadIdx.x) >> 6;
    int nw = (gridDim.x * 256) >> 6;
    for (unsigned p = gw; p < n; p += nw) {
        unsigned e = list[p];
        int b = e >> 18, i = (e >> 9) & 511, j = e & 511;
        const float* xb = x + (size_t)b * TT * NN;
        double s = 0.0;
        for (int t = lane; t < TT; t += 64)
            s += (double)xb[(size_t)t * NN + i] * (double)xb[(size_t)t * NN + j];
        #pragma unroll
        for (int o = 32; o > 0; o >>= 1)
            s += __shfl_xor(s, o, 64);
        if (lane == 0) {
            double cov = s - (double)s1[(size_t)b * NN + i]
                             * (double)s1[(size_t)b * NN + j] / (double)TT;
            double lim = (double)THR * (double)THR
                         * (double)dv[(size_t)b * NN + i]
                         * (double)dv[(size_t)b * NN + j];
            if (cov * cov > lim) atomicOr(&fired[(size_t)b * NN + i], 1u);
        }
    }
}

// ---------------- kernel C: finalize mask ----------------
__global__ __launch_bounds__(512) void finalize_mask(
    const unsigned* __restrict__ fired, float* __restrict__ out) {
    int b = blockIdx.x;
    int n = threadIdx.x;
    unsigned f = fired[(size_t)b * NN + n];
    __shared__ int wsum[8];
    unsigned long long m = __ballot(f != 0u);
    int lane = n & 63;
    int w = n >> 6;
    if (lane == 0) wsum[w] = __popcll(m);
    __syncthreads();
    int cnt = 0;
    #pragma unroll
    for (int i = 0; i < 8; ++i) cnt += wsum[i];
    float val = (cnt == 0) ? 1.0f : ((cnt == 1) ? (f ? 1.0f : 0.0f) : 0.0f);
    out[(size_t)b * NN + n] = val;
}

extern "C" void kernel_launch(void* const* d_in, const int* in_sizes, int n_in,
                              void* d_out, int out_size, void* d_ws, size_t ws_size,
                              hipStream_t stream) {
    const float* x = (const float*)d_in[0];
    float* out = (float*)d_out;

    // ws layout (~66 MB)
    ushort* xbf = (ushort*)d_ws;                         // BB*NN*TT bf16 = 64 MB
    float* s1 = (float*)(xbf + (size_t)BB * NN * TT);    // B*N
    float* dv = s1 + (size_t)BB * NN;                    // B*N
    float* nv = dv + (size_t)BB * NN;                    // B*N
    float* nl = nv + (size_t)BB * NN;                    // B*N
    unsigned* fired = (unsigned*)(nl + (size_t)BB * NN); // B*N
    unsigned* cnt   = fired + (size_t)BB * NN;           // 16 (padded)
    unsigned* list  = cnt + 16;                          // LISTCAP

    hipMemsetAsync(fired, 0, ((size_t)BB * NN + 16) * sizeof(unsigned), stream);

    transpose_colsum<<<dim3(BB, 8), 512, 0, stream>>>(x, xbf, s1, dv, nv, nl);
    corr_mfma<<<dim3(640), 512, 0, stream>>>(xbf, s1, dv, nv, nl, fired, cnt, list);
    cleanup_pairs<<<128, 256, 0, stream>>>(x, s1, dv, cnt, list, fired);
    finalize_mask<<<BB, 512, 0, stream>>>(fired, out);
}